// Round 2
// baseline (429.532 us; speedup 1.0000x reference)
//
#include <hip/hip_runtime.h>
#include <hip/hip_bf16.h>

#define NUM 8192
#define DIM 256

typedef __bf16 bf16x8 __attribute__((ext_vector_type(8)));
typedef float f32x4 __attribute__((ext_vector_type(4)));

// float -> bf16 round-to-nearest-even
__device__ __forceinline__ unsigned short f2bf(float x) {
  unsigned int u = __float_as_uint(x);
  unsigned int r = (u + 0x7FFFu + ((u >> 16) & 1u)) >> 16;
  return (unsigned short)r;
}

// async global->LDS, 16B per lane. LDS dest must be wave-uniform base + lane*16.
__device__ __forceinline__ void async_copy16(const void* g, void* l) {
  __builtin_amdgcn_global_load_lds(
      (const __attribute__((address_space(1))) void*)g,
      (__attribute__((address_space(3))) void*)l,
      16, 0, 0);
}

// ---------------------------------------------------------------------------
// prep: gather rows, compute row 1/||x||, write normalized bf16 (row-major)
// and raw bf16 transposed ET [DIM][NUM]. Also zeroes d_out (replaces memset).
// grid (128, 2), block 256
// ---------------------------------------------------------------------------
__global__ __launch_bounds__(256) void prep_kernel(
    const float* __restrict__ e1, const float* __restrict__ e2,
    const int* __restrict__ idx1, const int* __restrict__ idx2,
    unsigned short* __restrict__ En1, unsigned short* __restrict__ En2,
    unsigned short* __restrict__ ET1, unsigned short* __restrict__ ET2,
    float* __restrict__ d_out) {
  __shared__ float tile[64][260];  // 260: keeps float4 16B alignment per row
  __shared__ float rinv[64];
  const int t = threadIdx.x;
  const int mat = blockIdx.y;
  if (blockIdx.x == 0 && mat == 0 && t < 2) d_out[t] = 0.f;
  const float* E = mat ? e2 : e1;
  const int* idx = mat ? idx2 : idx1;
  unsigned short* En = mat ? En2 : En1;
  unsigned short* ET = mat ? ET2 : ET1;
  const int r0 = blockIdx.x * 64;

  // load 64 gathered rows x 256 cols (fp32, coalesced float4)
#pragma unroll
  for (int p = 0; p < 16; ++p) {
    int flat = p * 256 + t;   // float4 id, 4096 total = 64 rows * 64
    int row = flat >> 6;
    int c4 = flat & 63;
    int src = idx[r0 + row];
    float4 v = *(const float4*)(E + (size_t)src * DIM + c4 * 4);
    *(float4*)(&tile[row][c4 * 4]) = v;
  }
  __syncthreads();

  // row energies: 4 threads per row; column-interleaved (stride 4) to spread
  // banks: bank = (4*row + 4*q + part) % 32 -> worst 2-way (free)
  {
    int row = t >> 2, part = t & 3;
    float s = 0.f;
#pragma unroll
    for (int q = 0; q < 64; ++q) {
      float x = tile[row][q * 4 + part];
      s += x * x;
    }
    s += __shfl_xor(s, 1, 64);
    s += __shfl_xor(s, 2, 64);
    if (part == 0) rinv[row] = rsqrtf(s);
  }
  __syncthreads();

  // write normalized bf16, row-major
#pragma unroll
  for (int p = 0; p < 16; ++p) {
    int flat = p * 256 + t;
    int row = flat >> 6;
    int c4 = flat & 63;
    float ri = rinv[row];
    float a = tile[row][c4 * 4 + 0] * ri;
    float b = tile[row][c4 * 4 + 1] * ri;
    float c = tile[row][c4 * 4 + 2] * ri;
    float d = tile[row][c4 * 4 + 3] * ri;
    uint2 o;
    o.x = (unsigned int)f2bf(a) | ((unsigned int)f2bf(b) << 16);
    o.y = (unsigned int)f2bf(c) | ((unsigned int)f2bf(d) << 16);
    *(uint2*)(En + (size_t)(r0 + row) * DIM + c4 * 4) = o;
  }

  // write raw bf16 transposed: ET[c][r0..r0+64]
  {
    int g = t >> 5;
    int j = t & 31;
#pragma unroll
    for (int cc = 0; cc < 32; ++cc) {
      int c = g * 32 + cc;
      unsigned int lo = f2bf(tile[2 * j][c]);
      unsigned int hi = f2bf(tile[2 * j + 1][c]);
      *(unsigned int*)(ET + (size_t)c * NUM + r0 + 2 * j) = lo | (hi << 16);
    }
  }
}

// ---------------------------------------------------------------------------
// Shared tile machinery: 128x128 output tile, BK=64, 4 waves (64x64 each),
// XOR-swizzled LDS (logical chunk c of row r stored at physical c^(r&7)).
// ---------------------------------------------------------------------------
#define TILE_STAGE(GA, GB, STRIDE, COLBASE)                                   \
  {                                                                           \
    _Pragma("unroll")                                                         \
    for (int p = 0; p < 4; ++p) {                                             \
      int flat = p * 256 + t;                                                 \
      int row = flat >> 3, seg = flat & 7;                                    \
      int segx = seg ^ (row & 7);                                             \
      async_copy16((GA) + (size_t)row * (STRIDE) + (COLBASE) + segx * 8,      \
                   As + row * 64 + seg * 8);                                  \
    }                                                                         \
    _Pragma("unroll")                                                         \
    for (int p = 0; p < 4; ++p) {                                             \
      int flat = p * 256 + t;                                                 \
      int row = flat >> 3, seg = flat & 7;                                    \
      int segx = seg ^ (row & 7);                                             \
      async_copy16((GB) + (size_t)row * (STRIDE) + (COLBASE) + segx * 8,      \
                   Bs + row * 64 + seg * 8);                                  \
    }                                                                         \
  }

#define TILE_COMPUTE()                                                        \
  _Pragma("unroll")                                                           \
  for (int ks = 0; ks < 2; ++ks) {                                            \
    bf16x8 aF[4], bF[4];                                                      \
    const int swz = (ks * 4 + quad) ^ (l15 & 7);                              \
    _Pragma("unroll")                                                         \
    for (int i = 0; i < 4; ++i)                                               \
      aF[i] = *(const bf16x8*)(As + (wr + i * 16 + l15) * 64 + swz * 8);      \
    _Pragma("unroll")                                                         \
    for (int j = 0; j < 4; ++j)                                               \
      bF[j] = *(const bf16x8*)(Bs + (wc + j * 16 + l15) * 64 + swz * 8);      \
    _Pragma("unroll")                                                         \
    for (int i = 0; i < 4; ++i)                                               \
      _Pragma("unroll")                                                       \
      for (int j = 0; j < 4; ++j)                                             \
        acc[i][j] = __builtin_amdgcn_mfma_f32_16x16x32_bf16(aF[i], bF[j],     \
                                                            acc[i][j], 0, 0, 0); \
  }

#define GW_DOT(C, W)                                                          \
  sum += (W).x * (1.f - __expf((C).x - 1.f));                                 \
  sum += (W).y * (1.f - __expf((C).y - 1.f));                                 \
  sum += (W).z * (1.f - __expf((C).z - 1.f));                                 \
  sum += (W).w * (1.f - __expf((C).w - 1.f));

// Main-path K-step with counted vmcnt (T4): stage retires (vmcnt(4)), the
// 4 trans loads issued this step stay in flight ACROSS the raw s_barrier
// (no __syncthreads -> no compiler-forced vmcnt(0) drain). Trans group KK
// pairs with acc[KK][*] (column offset KK*16 in the cos^T tile).
#define MAIN_STEP(KK, TW)                                                     \
  TILE_STAGE(gA, gB, DIM, (KK) * 64);                                         \
  _Pragma("unroll")                                                           \
  for (int j = 0; j < 4; ++j)                                                 \
    TW[j] = __builtin_nontemporal_load(                                       \
        (const f32x4*)(tbase + (size_t)(j * 16) * NUM + (KK) * 16));          \
  asm volatile("s_waitcnt vmcnt(4)" ::: "memory");                            \
  asm volatile("s_barrier" ::: "memory");                                     \
  TILE_COMPUTE();

// ---------------------------------------------------------------------------
// fused: blocks 0..127 = gram partials (G = ET(128 rows) @ ET(128 rows)^T over
// a 512-wide K chunk); blocks 128..4223 = main cos/trans tile kernel.
// ---------------------------------------------------------------------------
__global__ __launch_bounds__(256) void fused_kernel(
    const unsigned short* __restrict__ En1,
    const unsigned short* __restrict__ En2,
    const unsigned short* __restrict__ ET1,
    const unsigned short* __restrict__ ET2,
    const float* __restrict__ trans,
    float* __restrict__ partials,
    float* __restrict__ d_out) {
  __shared__ unsigned short As[128 * 64];
  __shared__ unsigned short Bs[128 * 64];
  const int bid = blockIdx.x;
  const int t = threadIdx.x;
  const int wave = t >> 6, lane = t & 63;
  const int quad = lane >> 4, l15 = lane & 15;
  const int wr = (wave >> 1) * 64, wc = (wave & 1) * 64;

  f32x4 acc[4][4];
#pragma unroll
  for (int i = 0; i < 4; ++i)
#pragma unroll
    for (int j = 0; j < 4; ++j) {
      acc[i][j].x = 0.f; acc[i][j].y = 0.f; acc[i][j].z = 0.f; acc[i][j].w = 0.f;
    }

  if (bid < 128) {
    // ---- gram path: bid = (mat*4 + quadrant)*16 + kc ----
    const int mat = bid >> 6;
    const int quadrant = (bid >> 4) & 3;
    const int kc = bid & 15;
    const unsigned short* ET = mat ? ET2 : ET1;
    const int qi = quadrant >> 1, qj = quadrant & 1;
    const unsigned short* gA = ET + (size_t)(qi * 128) * NUM + kc * 512;
    const unsigned short* gB = ET + (size_t)(qj * 128) * NUM + kc * 512;

    for (int kk = 0; kk < 8; ++kk) {
      TILE_STAGE(gA, gB, NUM, kk * 64);
      asm volatile("s_waitcnt vmcnt(0)" ::: "memory");
      __syncthreads();
      TILE_COMPUTE();
      if (kk < 7) __syncthreads();
    }

    float* pw = partials + (size_t)bid * 16384;
#pragma unroll
    for (int i = 0; i < 4; ++i)
#pragma unroll
      for (int r = 0; r < 4; ++r) {
        int rl = wr + i * 16 + quad * 4 + r;
#pragma unroll
        for (int j = 0; j < 4; ++j) {
          int cl = wc + j * 16 + l15;
          float v = (r == 0) ? acc[i][j].x : (r == 1) ? acc[i][j].y
                  : (r == 2) ? acc[i][j].z : acc[i][j].w;
          pw[rl * 128 + cl] = v;
        }
      }
  } else {
    // ---- main path: OPERAND-SWAPPED 128x128 tile, acc = cos^T ----
    const int g = bid - 128;
    const int bx = g & 63;   // En2 tile
    const int by = g >> 6;   // En1 tile
    const unsigned short* gA = En2 + (size_t)(bx * 128) * DIM;
    const unsigned short* gB = En1 + (size_t)(by * 128) * DIM;
    // trans base for this thread: row = En1 idx (by*128 + wc + j*16 + l15),
    // col = En2 idx (bx*128 + wr + i*16 + quad*4). Group i loads at +i*16.
    const float* tbase = trans + (size_t)(by * 128 + wc + l15) * NUM
                               + (size_t)(bx * 128 + wr + quad * 4);

    f32x4 tw0[4], tw1[4], tw2[4], tw3[4];

    // Counted-vmcnt pipeline: per-wave issue ledger
    // [S0 x8][T0 x4] W(4) | [S1 x8][T1 x4] W(4) | ... — each W(4) retires the
    // prior trans group + this step's stage, leaving the newest 4 trans loads
    // airborne across the raw barrier. Trans bytes stream during the GEMM.
    MAIN_STEP(0, tw0);
    asm volatile("s_barrier" ::: "memory");
    MAIN_STEP(1, tw1);
    asm volatile("s_barrier" ::: "memory");
    MAIN_STEP(2, tw2);
    asm volatile("s_barrier" ::: "memory");
    MAIN_STEP(3, tw3);
    // no trailing barrier: LDS not re-staged; tw3 waited by compiler at use.

    float sum = 0.f;
#pragma unroll
    for (int j = 0; j < 4; ++j) {
      GW_DOT(acc[0][j], tw0[j]);
      GW_DOT(acc[1][j], tw1[j]);
      GW_DOT(acc[2][j], tw2[j]);
      GW_DOT(acc[3][j], tw3[j]);
    }
#pragma unroll
    for (int off = 32; off > 0; off >>= 1) sum += __shfl_down(sum, off, 64);
    __shared__ float wsum[4];
    if (lane == 0) wsum[wave] = sum;
    __syncthreads();
    if (t == 0) atomicAdd(d_out, wsum[0] + wsum[1] + wsum[2] + wsum[3]);
  }
}

// ---------------------------------------------------------------------------
// gram reduce: sum k-chunk partials, subtract I, square, reduce -> d_out[1]
// ---------------------------------------------------------------------------
__global__ __launch_bounds__(256) void gram_reduce_kernel(
    const float* __restrict__ partials, float* __restrict__ d_out) {
  int e = blockIdx.x * 256 + threadIdx.x;  // 0..131071
  int mat = e >> 16;
  int rem = e & 65535;
  int quadrant = rem >> 14;
  int li = rem & 16383;
  const float* p = partials + ((size_t)(mat * 4 + quadrant) * 16) * 16384 + li;
  float g = 0.f;
#pragma unroll
  for (int kc = 0; kc < 16; ++kc) g += p[(size_t)kc * 16384];
  int rl = li >> 7, cl = li & 127;
  int gr = (quadrant >> 1) * 128 + rl;
  int gc = (quadrant & 1) * 128 + cl;
  if (gr == gc) g -= 1.f;
  float s = g * g;
#pragma unroll
  for (int off = 32; off > 0; off >>= 1) s += __shfl_down(s, off, 64);
  __shared__ float wsum[4];
  int wave = threadIdx.x >> 6, lane = threadIdx.x & 63;
  if (lane == 0) wsum[wave] = s;
  __syncthreads();
  if (threadIdx.x == 0) atomicAdd(d_out + 1, wsum[0] + wsum[1] + wsum[2] + wsum[3]);
}

// ---------------------------------------------------------------------------
extern "C" void kernel_launch(void* const* d_in, const int* in_sizes, int n_in,
                              void* d_out, int out_size, void* d_ws, size_t ws_size,
                              hipStream_t stream) {
  const int* idx1 = (const int*)d_in[0];
  const int* idx2 = (const int*)d_in[1];
  const float* trans = (const float*)d_in[2];
  const float* e1 = (const float*)d_in[3];
  const float* e2 = (const float*)d_in[4];
  float* out = (float*)d_out;

  char* ws = (char*)d_ws;
  unsigned short* En1 = (unsigned short*)(ws);                    // 4 MB
  unsigned short* En2 = (unsigned short*)(ws + (4u << 20));       // 4 MB
  unsigned short* ET1 = (unsigned short*)(ws + (8u << 20));       // 4 MB
  unsigned short* ET2 = (unsigned short*)(ws + (12u << 20));      // 4 MB
  float* partials = (float*)(ws + (16u << 20));                   // 8 MB

  hipLaunchKernelGGL(prep_kernel, dim3(128, 2), dim3(256), 0, stream,
                     e1, e2, idx1, idx2, En1, En2, ET1, ET2, out);
  hipLaunchKernelGGL(fused_kernel, dim3(4224), dim3(256), 0, stream,
                     En1, En2, ET1, ET2, trans, partials, out);
  hipLaunchKernelGGL(gram_reduce_kernel, dim3(512), dim3(256), 0, stream,
                     partials, out);
}

// Round 3
// 427.146 us; speedup vs baseline: 1.0056x; 1.0056x over previous
//
#include <hip/hip_runtime.h>
#include <hip/hip_bf16.h>

#define NUM 8192
#define DIM 256

typedef __bf16 bf16x8 __attribute__((ext_vector_type(8)));
typedef float f32x4 __attribute__((ext_vector_type(4)));

// float -> bf16 round-to-nearest-even
__device__ __forceinline__ unsigned short f2bf(float x) {
  unsigned int u = __float_as_uint(x);
  unsigned int r = (u + 0x7FFFu + ((u >> 16) & 1u)) >> 16;
  return (unsigned short)r;
}

// async global->LDS, 16B per lane. LDS dest must be wave-uniform base + lane*16.
__device__ __forceinline__ void async_copy16(const void* g, void* l) {
  __builtin_amdgcn_global_load_lds(
      (const __attribute__((address_space(1))) void*)g,
      (__attribute__((address_space(3))) void*)l,
      16, 0, 0);
}

// ---------------------------------------------------------------------------
// prep: gather rows, compute row 1/||x||, write normalized bf16 (row-major)
// and raw bf16 transposed ET [DIM][NUM]. Also zeroes d_out (replaces memset).
// grid (128, 2), block 256
// ---------------------------------------------------------------------------
__global__ __launch_bounds__(256) void prep_kernel(
    const float* __restrict__ e1, const float* __restrict__ e2,
    const int* __restrict__ idx1, const int* __restrict__ idx2,
    unsigned short* __restrict__ En1, unsigned short* __restrict__ En2,
    unsigned short* __restrict__ ET1, unsigned short* __restrict__ ET2,
    float* __restrict__ d_out) {
  __shared__ float tile[64][260];  // 260: keeps float4 16B alignment per row
  __shared__ float rinv[64];
  const int t = threadIdx.x;
  const int mat = blockIdx.y;
  if (blockIdx.x == 0 && mat == 0 && t < 2) d_out[t] = 0.f;
  const float* E = mat ? e2 : e1;
  const int* idx = mat ? idx2 : idx1;
  unsigned short* En = mat ? En2 : En1;
  unsigned short* ET = mat ? ET2 : ET1;
  const int r0 = blockIdx.x * 64;

  // load 64 gathered rows x 256 cols (fp32, coalesced float4)
#pragma unroll
  for (int p = 0; p < 16; ++p) {
    int flat = p * 256 + t;   // float4 id, 4096 total = 64 rows * 64
    int row = flat >> 6;
    int c4 = flat & 63;
    int src = idx[r0 + row];
    float4 v = *(const float4*)(E + (size_t)src * DIM + c4 * 4);
    *(float4*)(&tile[row][c4 * 4]) = v;
  }
  __syncthreads();

  // row energies: 4 threads per row; column-interleaved (stride 4) to spread
  // banks: bank = (4*row + 4*q + part) % 32 -> worst 2-way (free)
  {
    int row = t >> 2, part = t & 3;
    float s = 0.f;
#pragma unroll
    for (int q = 0; q < 64; ++q) {
      float x = tile[row][q * 4 + part];
      s += x * x;
    }
    s += __shfl_xor(s, 1, 64);
    s += __shfl_xor(s, 2, 64);
    if (part == 0) rinv[row] = rsqrtf(s);
  }
  __syncthreads();

  // write normalized bf16, row-major
#pragma unroll
  for (int p = 0; p < 16; ++p) {
    int flat = p * 256 + t;
    int row = flat >> 6;
    int c4 = flat & 63;
    float ri = rinv[row];
    float a = tile[row][c4 * 4 + 0] * ri;
    float b = tile[row][c4 * 4 + 1] * ri;
    float c = tile[row][c4 * 4 + 2] * ri;
    float d = tile[row][c4 * 4 + 3] * ri;
    uint2 o;
    o.x = (unsigned int)f2bf(a) | ((unsigned int)f2bf(b) << 16);
    o.y = (unsigned int)f2bf(c) | ((unsigned int)f2bf(d) << 16);
    *(uint2*)(En + (size_t)(r0 + row) * DIM + c4 * 4) = o;
  }

  // write raw bf16 transposed: ET[c][r0..r0+64]
  {
    int g = t >> 5;
    int j = t & 31;
#pragma unroll
    for (int cc = 0; cc < 32; ++cc) {
      int c = g * 32 + cc;
      unsigned int lo = f2bf(tile[2 * j][c]);
      unsigned int hi = f2bf(tile[2 * j + 1][c]);
      *(unsigned int*)(ET + (size_t)c * NUM + r0 + 2 * j) = lo | (hi << 16);
    }
  }
}

// ---------------------------------------------------------------------------
// Shared tile machinery: 128x128 output tile, BK=64, 4 waves (64x64 each),
// XOR-swizzled LDS (logical chunk c of row r stored at physical c^(r&7)).
// ---------------------------------------------------------------------------
#define TILE_STAGE(GA, GB, STRIDE, COLBASE)                                   \
  {                                                                           \
    _Pragma("unroll")                                                         \
    for (int p = 0; p < 4; ++p) {                                             \
      int flat = p * 256 + t;                                                 \
      int row = flat >> 3, seg = flat & 7;                                    \
      int segx = seg ^ (row & 7);                                             \
      async_copy16((GA) + (size_t)row * (STRIDE) + (COLBASE) + segx * 8,      \
                   As + row * 64 + seg * 8);                                  \
    }                                                                         \
    _Pragma("unroll")                                                         \
    for (int p = 0; p < 4; ++p) {                                             \
      int flat = p * 256 + t;                                                 \
      int row = flat >> 3, seg = flat & 7;                                    \
      int segx = seg ^ (row & 7);                                             \
      async_copy16((GB) + (size_t)row * (STRIDE) + (COLBASE) + segx * 8,      \
                   Bs + row * 64 + seg * 8);                                  \
    }                                                                         \
  }

// stage one 32-row x 128-col f32 trans chunk (16 KB) into LDS at DST.
// Logical 16B segment seg of row stored at physical seg (linear LDS dest);
// the XOR swizzle is applied on the GLOBAL source segment (m173 pattern), so
// epilogue reads use phys = seg_log ^ (row & 7) and hit 8 distinct segments
// across l15&7 -> 2-way (free) bank access.
#define TRANS_STAGE(CH, DST)                                                  \
  {                                                                           \
    _Pragma("unroll")                                                         \
    for (int p = 0; p < 4; ++p) {                                             \
      int flat = p * 256 + t;   /* 0..1023 = row*32+seg */                    \
      int row = flat >> 5, seg = flat & 31;                                   \
      int segx = seg ^ (row & 7);                                             \
      async_copy16(tblk + (size_t)((CH) * 32 + row) * NUM + segx * 4,         \
                   (float*)(DST) + (size_t)flat * 4);                         \
    }                                                                         \
  }

#define TILE_COMPUTE()                                                        \
  _Pragma("unroll")                                                           \
  for (int ks = 0; ks < 2; ++ks) {                                            \
    bf16x8 aF[4], bF[4];                                                      \
    const int swz = (ks * 4 + quad) ^ (l15 & 7);                              \
    _Pragma("unroll")                                                         \
    for (int i = 0; i < 4; ++i)                                               \
      aF[i] = *(const bf16x8*)(As + (wr + i * 16 + l15) * 64 + swz * 8);      \
    _Pragma("unroll")                                                         \
    for (int j = 0; j < 4; ++j)                                               \
      bF[j] = *(const bf16x8*)(Bs + (wc + j * 16 + l15) * 64 + swz * 8);      \
    _Pragma("unroll")                                                         \
    for (int i = 0; i < 4; ++i)                                               \
      _Pragma("unroll")                                                       \
      for (int j = 0; j < 4; ++j)                                             \
        acc[i][j] = __builtin_amdgcn_mfma_f32_16x16x32_bf16(aF[i], bF[j],     \
                                                            acc[i][j], 0, 0, 0); \
  }

#define GW_DOT(C, W)                                                          \
  sum += (W).x * (1.f - __expf((C).x - 1.f));                                 \
  sum += (W).y * (1.f - __expf((C).y - 1.f));                                 \
  sum += (W).z * (1.f - __expf((C).z - 1.f));                                 \
  sum += (W).w * (1.f - __expf((C).w - 1.f));

// ---------------------------------------------------------------------------
// fused: blocks 0..127 = gram partials (G = ET(128 rows) @ ET(128 rows)^T over
// a 512-wide K chunk); blocks 128..4223 = main cos/trans tile kernel.
// Main path streams the 64 KB trans tile into LDS DURING the K-loop (chunks
// ride the per-step vmcnt(0) drain), so HBM stays busy through the GEMM and
// the kernel paces to the 256 MB trans BW floor instead of serializing a
// trans burst after the MFMAs.
// ---------------------------------------------------------------------------
__global__ __launch_bounds__(256) void fused_kernel(
    const unsigned short* __restrict__ En1,
    const unsigned short* __restrict__ En2,
    const unsigned short* __restrict__ ET1,
    const unsigned short* __restrict__ ET2,
    const float* __restrict__ trans,
    float* __restrict__ partials,
    float* __restrict__ d_out) {
  __shared__ unsigned short As[128 * 64];  // 16 KB
  __shared__ unsigned short Bs[128 * 64];  // 16 KB (reused for trans chunk 3)
  __shared__ float Ts[3 * 4096];           // 48 KB: trans chunks 0..2
  const int bid = blockIdx.x;
  const int t = threadIdx.x;
  const int wave = t >> 6, lane = t & 63;
  const int quad = lane >> 4, l15 = lane & 15;
  const int wr = (wave >> 1) * 64, wc = (wave & 1) * 64;

  f32x4 acc[4][4];
#pragma unroll
  for (int i = 0; i < 4; ++i)
#pragma unroll
    for (int j = 0; j < 4; ++j) {
      acc[i][j].x = 0.f; acc[i][j].y = 0.f; acc[i][j].z = 0.f; acc[i][j].w = 0.f;
    }

  if (bid < 128) {
    // ---- gram path: bid = (mat*4 + quadrant)*16 + kc ----
    const int mat = bid >> 6;
    const int quadrant = (bid >> 4) & 3;
    const int kc = bid & 15;
    const unsigned short* ET = mat ? ET2 : ET1;
    const int qi = quadrant >> 1, qj = quadrant & 1;
    const unsigned short* gA = ET + (size_t)(qi * 128) * NUM + kc * 512;
    const unsigned short* gB = ET + (size_t)(qj * 128) * NUM + kc * 512;

    for (int kk = 0; kk < 8; ++kk) {
      TILE_STAGE(gA, gB, NUM, kk * 64);
      asm volatile("s_waitcnt vmcnt(0)" ::: "memory");
      __syncthreads();
      TILE_COMPUTE();
      if (kk < 7) __syncthreads();
    }

    float* pw = partials + (size_t)bid * 16384;
#pragma unroll
    for (int i = 0; i < 4; ++i)
#pragma unroll
      for (int r = 0; r < 4; ++r) {
        int rl = wr + i * 16 + quad * 4 + r;
#pragma unroll
        for (int j = 0; j < 4; ++j) {
          int cl = wc + j * 16 + l15;
          float v = (r == 0) ? acc[i][j].x : (r == 1) ? acc[i][j].y
                  : (r == 2) ? acc[i][j].z : acc[i][j].w;
          pw[rl * 128 + cl] = v;
        }
      }
  } else {
    // ---- main path: OPERAND-SWAPPED 128x128 tile, acc = cos^T ----
    const int g = bid - 128;
    const int bx = g & 63;   // En2 tile
    const int by = g >> 6;   // En1 tile
    const unsigned short* gA = En2 + (size_t)(bx * 128) * DIM;
    const unsigned short* gB = En1 + (size_t)(by * 128) * DIM;
    // block's trans tile origin: rows = En1 ids (by*128+), cols = En2 (bx*128+)
    const float* tblk = trans + (size_t)(by * 128) * NUM + bx * 128;

    // K-step 0: En stage only (cold start)
    TILE_STAGE(gA, gB, DIM, 0);
    asm volatile("s_waitcnt vmcnt(0)" ::: "memory");
    __syncthreads();
    TILE_COMPUTE();
    // K-steps 1..3: En stage + one 16 KB trans chunk each (drained together)
#pragma unroll
    for (int kk = 1; kk < 4; ++kk) {
      __syncthreads();
      TILE_STAGE(gA, gB, DIM, kk * 64);
      TRANS_STAGE(kk - 1, Ts + (size_t)(kk - 1) * 4096);
      asm volatile("s_waitcnt vmcnt(0)" ::: "memory");
      __syncthreads();
      TILE_COMPUTE();
    }
    // chunk 3 reuses Bs (exactly 16 KB) once all waves are done reading it
    __syncthreads();
    TRANS_STAGE(3, Bs);
    asm volatile("s_waitcnt vmcnt(0)" ::: "memory");
    __syncthreads();

    // epilogue: acc[i][j] reg r = cos(En1[by*128+wc+j*16+l15],
    //                                En2[bx*128+wr+i*16+quad*4+r]).
    // trans from LDS: row r1 = wc+j*16+l15 -> chunk r1>>5, row r1&31;
    // col segment logical = wr/4 + i*4 + quad, physical = log ^ (row&7).
    float sum = 0.f;
#pragma unroll
    for (int j = 0; j < 4; ++j) {
      int r1 = wc + j * 16 + l15;
      int ch = r1 >> 5, r = r1 & 31;
      const float* cb = (ch == 3) ? (const float*)Bs : Ts + (size_t)ch * 4096;
      int segl = (wr >> 2) + quad;
#pragma unroll
      for (int i = 0; i < 4; ++i) {
        int seg = (segl + i * 4) ^ (r & 7);
        f32x4 w = *(const f32x4*)(cb + ((size_t)r * 32 + seg) * 4);
        GW_DOT(acc[i][j], w);
      }
    }
#pragma unroll
    for (int off = 32; off > 0; off >>= 1) sum += __shfl_down(sum, off, 64);
    __shared__ float wsum[4];
    if (lane == 0) wsum[wave] = sum;
    __syncthreads();
    if (t == 0) atomicAdd(d_out, wsum[0] + wsum[1] + wsum[2] + wsum[3]);
  }
}

// ---------------------------------------------------------------------------
// gram reduce: sum k-chunk partials, subtract I, square, reduce -> d_out[1]
// ---------------------------------------------------------------------------
__global__ __launch_bounds__(256) void gram_reduce_kernel(
    const float* __restrict__ partials, float* __restrict__ d_out) {
  int e = blockIdx.x * 256 + threadIdx.x;  // 0..131071
  int mat = e >> 16;
  int rem = e & 65535;
  int quadrant = rem >> 14;
  int li = rem & 16383;
  const float* p = partials + ((size_t)(mat * 4 + quadrant) * 16) * 16384 + li;
  float g = 0.f;
#pragma unroll
  for (int kc = 0; kc < 16; ++kc) g += p[(size_t)kc * 16384];
  int rl = li >> 7, cl = li & 127;
  int gr = (quadrant >> 1) * 128 + rl;
  int gc = (quadrant & 1) * 128 + cl;
  if (gr == gc) g -= 1.f;
  float s = g * g;
#pragma unroll
  for (int off = 32; off > 0; off >>= 1) s += __shfl_down(s, off, 64);
  __shared__ float wsum[4];
  int wave = threadIdx.x >> 6, lane = threadIdx.x & 63;
  if (lane == 0) wsum[wave] = s;
  __syncthreads();
  if (threadIdx.x == 0) atomicAdd(d_out + 1, wsum[0] + wsum[1] + wsum[2] + wsum[3]);
}

// ---------------------------------------------------------------------------
extern "C" void kernel_launch(void* const* d_in, const int* in_sizes, int n_in,
                              void* d_out, int out_size, void* d_ws, size_t ws_size,
                              hipStream_t stream) {
  const int* idx1 = (const int*)d_in[0];
  const int* idx2 = (const int*)d_in[1];
  const float* trans = (const float*)d_in[2];
  const float* e1 = (const float*)d_in[3];
  const float* e2 = (const float*)d_in[4];
  float* out = (float*)d_out;

  char* ws = (char*)d_ws;
  unsigned short* En1 = (unsigned short*)(ws);                    // 4 MB
  unsigned short* En2 = (unsigned short*)(ws + (4u << 20));       // 4 MB
  unsigned short* ET1 = (unsigned short*)(ws + (8u << 20));       // 4 MB
  unsigned short* ET2 = (unsigned short*)(ws + (12u << 20));      // 4 MB
  float* partials = (float*)(ws + (16u << 20));                   // 8 MB

  hipLaunchKernelGGL(prep_kernel, dim3(128, 2), dim3(256), 0, stream,
                     e1, e2, idx1, idx2, En1, En2, ET1, ET2, out);
  hipLaunchKernelGGL(fused_kernel, dim3(4224), dim3(256), 0, stream,
                     En1, En2, ET1, ET2, trans, partials, out);
  hipLaunchKernelGGL(gram_reduce_kernel, dim3(512), dim3(256), 0, stream,
                     partials, out);
}

// Round 4
// 418.298 us; speedup vs baseline: 1.0269x; 1.0212x over previous
//
#include <hip/hip_runtime.h>
#include <hip/hip_bf16.h>

#define NUM 8192
#define DIM 256

typedef __bf16 bf16x8 __attribute__((ext_vector_type(8)));
typedef float f32x4 __attribute__((ext_vector_type(4)));

// float -> bf16 round-to-nearest-even
__device__ __forceinline__ unsigned short f2bf(float x) {
  unsigned int u = __float_as_uint(x);
  unsigned int r = (u + 0x7FFFu + ((u >> 16) & 1u)) >> 16;
  return (unsigned short)r;
}

// async global->LDS, 16B per lane. LDS dest must be wave-uniform base + lane*16.
__device__ __forceinline__ void async_copy16(const void* g, void* l) {
  __builtin_amdgcn_global_load_lds(
      (const __attribute__((address_space(1))) void*)g,
      (__attribute__((address_space(3))) void*)l,
      16, 0, 0);
}

// ---------------------------------------------------------------------------
// prep: gather rows, compute row 1/||x||, write normalized bf16 (row-major)
// and raw bf16 transposed ET [DIM][NUM]. Also zeroes d_out (replaces memset).
// grid (128, 2), block 256
// ---------------------------------------------------------------------------
__global__ __launch_bounds__(256) void prep_kernel(
    const float* __restrict__ e1, const float* __restrict__ e2,
    const int* __restrict__ idx1, const int* __restrict__ idx2,
    unsigned short* __restrict__ En1, unsigned short* __restrict__ En2,
    unsigned short* __restrict__ ET1, unsigned short* __restrict__ ET2,
    float* __restrict__ d_out) {
  __shared__ float tile[64][260];  // 260: keeps float4 16B alignment per row
  __shared__ float rinv[64];
  const int t = threadIdx.x;
  const int mat = blockIdx.y;
  if (blockIdx.x == 0 && mat == 0 && t < 2) d_out[t] = 0.f;
  const float* E = mat ? e2 : e1;
  const int* idx = mat ? idx2 : idx1;
  unsigned short* En = mat ? En2 : En1;
  unsigned short* ET = mat ? ET2 : ET1;
  const int r0 = blockIdx.x * 64;

  // load 64 gathered rows x 256 cols (fp32, coalesced float4)
#pragma unroll
  for (int p = 0; p < 16; ++p) {
    int flat = p * 256 + t;   // float4 id, 4096 total = 64 rows * 64
    int row = flat >> 6;
    int c4 = flat & 63;
    int src = idx[r0 + row];
    float4 v = *(const float4*)(E + (size_t)src * DIM + c4 * 4);
    *(float4*)(&tile[row][c4 * 4]) = v;
  }
  __syncthreads();

  // row energies: 4 threads per row; column-interleaved (stride 4) to spread
  // banks: bank = (4*row + 4*q + part) % 32 -> worst 2-way (free)
  {
    int row = t >> 2, part = t & 3;
    float s = 0.f;
#pragma unroll
    for (int q = 0; q < 64; ++q) {
      float x = tile[row][q * 4 + part];
      s += x * x;
    }
    s += __shfl_xor(s, 1, 64);
    s += __shfl_xor(s, 2, 64);
    if (part == 0) rinv[row] = rsqrtf(s);
  }
  __syncthreads();

  // write normalized bf16, row-major
#pragma unroll
  for (int p = 0; p < 16; ++p) {
    int flat = p * 256 + t;
    int row = flat >> 6;
    int c4 = flat & 63;
    float ri = rinv[row];
    float a = tile[row][c4 * 4 + 0] * ri;
    float b = tile[row][c4 * 4 + 1] * ri;
    float c = tile[row][c4 * 4 + 2] * ri;
    float d = tile[row][c4 * 4 + 3] * ri;
    uint2 o;
    o.x = (unsigned int)f2bf(a) | ((unsigned int)f2bf(b) << 16);
    o.y = (unsigned int)f2bf(c) | ((unsigned int)f2bf(d) << 16);
    *(uint2*)(En + (size_t)(r0 + row) * DIM + c4 * 4) = o;
  }

  // write raw bf16 transposed: ET[c][r0..r0+64]
  {
    int g = t >> 5;
    int j = t & 31;
#pragma unroll
    for (int cc = 0; cc < 32; ++cc) {
      int c = g * 32 + cc;
      unsigned int lo = f2bf(tile[2 * j][c]);
      unsigned int hi = f2bf(tile[2 * j + 1][c]);
      *(unsigned int*)(ET + (size_t)c * NUM + r0 + 2 * j) = lo | (hi << 16);
    }
  }
}

// ---------------------------------------------------------------------------
// Shared tile machinery: 128x128 output tile, BK=64, 4 waves (64x64 each),
// XOR-swizzled LDS (logical chunk c of row r stored at physical c^(r&7)).
// ---------------------------------------------------------------------------
#define TILE_STAGE(GA, GB, STRIDE, COLBASE)                                   \
  {                                                                           \
    _Pragma("unroll")                                                         \
    for (int p = 0; p < 4; ++p) {                                             \
      int flat = p * 256 + t;                                                 \
      int row = flat >> 3, seg = flat & 7;                                    \
      int segx = seg ^ (row & 7);                                             \
      async_copy16((GA) + (size_t)row * (STRIDE) + (COLBASE) + segx * 8,      \
                   As + row * 64 + seg * 8);                                  \
    }                                                                         \
    _Pragma("unroll")                                                         \
    for (int p = 0; p < 4; ++p) {                                             \
      int flat = p * 256 + t;                                                 \
      int row = flat >> 3, seg = flat & 7;                                    \
      int segx = seg ^ (row & 7);                                             \
      async_copy16((GB) + (size_t)row * (STRIDE) + (COLBASE) + segx * 8,      \
                   Bs + row * 64 + seg * 8);                                  \
    }                                                                         \
  }

#define TILE_COMPUTE()                                                        \
  _Pragma("unroll")                                                           \
  for (int ks = 0; ks < 2; ++ks) {                                            \
    bf16x8 aF[4], bF[4];                                                      \
    const int swz = (ks * 4 + quad) ^ (l15 & 7);                              \
    _Pragma("unroll")                                                         \
    for (int i = 0; i < 4; ++i)                                               \
      aF[i] = *(const bf16x8*)(As + (wr + i * 16 + l15) * 64 + swz * 8);      \
    _Pragma("unroll")                                                         \
    for (int j = 0; j < 4; ++j)                                               \
      bF[j] = *(const bf16x8*)(Bs + (wc + j * 16 + l15) * 64 + swz * 8);      \
    _Pragma("unroll")                                                         \
    for (int i = 0; i < 4; ++i)                                               \
      _Pragma("unroll")                                                       \
      for (int j = 0; j < 4; ++j)                                             \
        acc[i][j] = __builtin_amdgcn_mfma_f32_16x16x32_bf16(aF[i], bF[j],     \
                                                            acc[i][j], 0, 0, 0); \
  }

#define GW_DOT(C, W)                                                          \
  sum += (W).x * (1.f - __expf((C).x - 1.f));                                 \
  sum += (W).y * (1.f - __expf((C).y - 1.f));                                 \
  sum += (W).z * (1.f - __expf((C).z - 1.f));                                 \
  sum += (W).w * (1.f - __expf((C).w - 1.f));

// ---------------------------------------------------------------------------
// fused: blocks 0..127 = gram partials (G = ET(128 rows) @ ET(128 rows)^T over
// a 512-wide K chunk); blocks 128..4223 = main cos/trans tile kernel.
// Main path uses the R1 structure (best measured): plain __syncthreads K-loop,
// 16-deep MLP trans prefetch split around the last compute. New in R4: T1
// XCD-aware swizzle of the main block mapping — each XCD gets a contiguous
// by-range (8 En1 panels = 512 KB hot in its private 4 MB L2), so En panel
// re-reads are L2-served instead of L3-served, freeing the L3/HBM path for
// the 256 MB trans stream. 4096 % 8 == 0 -> swizzle is bijective.
// ---------------------------------------------------------------------------
__global__ __launch_bounds__(256) void fused_kernel(
    const unsigned short* __restrict__ En1,
    const unsigned short* __restrict__ En2,
    const unsigned short* __restrict__ ET1,
    const unsigned short* __restrict__ ET2,
    const float* __restrict__ trans,
    float* __restrict__ partials,
    float* __restrict__ d_out) {
  __shared__ unsigned short As[128 * 64];
  __shared__ unsigned short Bs[128 * 64];
  const int bid = blockIdx.x;
  const int t = threadIdx.x;
  const int wave = t >> 6, lane = t & 63;
  const int quad = lane >> 4, l15 = lane & 15;
  const int wr = (wave >> 1) * 64, wc = (wave & 1) * 64;

  f32x4 acc[4][4];
#pragma unroll
  for (int i = 0; i < 4; ++i)
#pragma unroll
    for (int j = 0; j < 4; ++j) {
      acc[i][j].x = 0.f; acc[i][j].y = 0.f; acc[i][j].z = 0.f; acc[i][j].w = 0.f;
    }

  if (bid < 128) {
    // ---- gram path: bid = (mat*4 + quadrant)*16 + kc ----
    const int mat = bid >> 6;
    const int quadrant = (bid >> 4) & 3;
    const int kc = bid & 15;
    const unsigned short* ET = mat ? ET2 : ET1;
    const int qi = quadrant >> 1, qj = quadrant & 1;
    const unsigned short* gA = ET + (size_t)(qi * 128) * NUM + kc * 512;
    const unsigned short* gB = ET + (size_t)(qj * 128) * NUM + kc * 512;

    for (int kk = 0; kk < 8; ++kk) {
      TILE_STAGE(gA, gB, NUM, kk * 64);
      asm volatile("s_waitcnt vmcnt(0)" ::: "memory");
      __syncthreads();
      TILE_COMPUTE();
      if (kk < 7) __syncthreads();
    }

    float* pw = partials + (size_t)bid * 16384;
#pragma unroll
    for (int i = 0; i < 4; ++i)
#pragma unroll
      for (int r = 0; r < 4; ++r) {
        int rl = wr + i * 16 + quad * 4 + r;
#pragma unroll
        for (int j = 0; j < 4; ++j) {
          int cl = wc + j * 16 + l15;
          float v = (r == 0) ? acc[i][j].x : (r == 1) ? acc[i][j].y
                  : (r == 2) ? acc[i][j].z : acc[i][j].w;
          pw[rl * 128 + cl] = v;
        }
      }
  } else {
    // ---- main path: OPERAND-SWAPPED 128x128 tile, acc = cos^T ----
    const int g0 = bid - 128;
    // T1 XCD swizzle: XCD k (= g0 % 8 under round-robin dispatch) owns the
    // contiguous logical range [k*512, (k+1)*512) = by in [k*8, (k+1)*8).
    const int g = (g0 & 7) * 512 + (g0 >> 3);
    const int bx = g & 63;   // En2 tile
    const int by = g >> 6;   // En1 tile
    const unsigned short* gA = En2 + (size_t)(bx * 128) * DIM;
    const unsigned short* gB = En1 + (size_t)(by * 128) * DIM;

    for (int kk = 0; kk < 3; ++kk) {  // K = 256, BK = 64
      TILE_STAGE(gA, gB, DIM, kk * 64);
      asm volatile("s_waitcnt vmcnt(0)" ::: "memory");
      __syncthreads();
      TILE_COMPUTE();
      __syncthreads();
    }
    // last K step: after the barrier, prefetch half the trans tile so the
    // HBM latency hides under the final 32 MFMAs. Half only (+32 VGPR peak)
    // to stay under the 170-VGPR / 3-waves-per-SIMD cliff.
    TILE_STAGE(gA, gB, DIM, 3 * 64);
    asm volatile("s_waitcnt vmcnt(0)" ::: "memory");
    __syncthreads();
    f32x4 tw0[4], tw1[4];
#pragma unroll
    for (int j = 0; j < 4; ++j) {
      size_t r1 = (size_t)(by * 128 + wc + j * 16 + l15);
      size_t cb = (size_t)(bx * 128 + wr + quad * 4);
      tw0[j] = __builtin_nontemporal_load((const f32x4*)(trans + r1 * NUM + cb));
      tw1[j] = __builtin_nontemporal_load((const f32x4*)(trans + r1 * NUM + cb + 16));
    }
    TILE_COMPUTE();

    // epilogue: acc[i][j] reg r holds cos(En1[by*128+wc+j*16+l15],
    //                                    En2[bx*128+wr+i*16+quad*4+r])
    f32x4 tw2[4], tw3[4];
#pragma unroll
    for (int j = 0; j < 4; ++j) {
      size_t r1 = (size_t)(by * 128 + wc + j * 16 + l15);
      size_t cb = (size_t)(bx * 128 + wr + quad * 4);
      tw2[j] = __builtin_nontemporal_load((const f32x4*)(trans + r1 * NUM + cb + 32));
      tw3[j] = __builtin_nontemporal_load((const f32x4*)(trans + r1 * NUM + cb + 48));
    }
    float sum = 0.f;
#pragma unroll
    for (int j = 0; j < 4; ++j) {
      GW_DOT(acc[0][j], tw0[j]);
      GW_DOT(acc[1][j], tw1[j]);
      GW_DOT(acc[2][j], tw2[j]);
      GW_DOT(acc[3][j], tw3[j]);
    }
#pragma unroll
    for (int off = 32; off > 0; off >>= 1) sum += __shfl_down(sum, off, 64);
    __shared__ float wsum[4];
    if (lane == 0) wsum[wave] = sum;
    __syncthreads();
    if (t == 0) atomicAdd(d_out, wsum[0] + wsum[1] + wsum[2] + wsum[3]);
  }
}

// ---------------------------------------------------------------------------
// gram reduce: sum k-chunk partials, subtract I, square, reduce -> d_out[1]
// ---------------------------------------------------------------------------
__global__ __launch_bounds__(256) void gram_reduce_kernel(
    const float* __restrict__ partials, float* __restrict__ d_out) {
  int e = blockIdx.x * 256 + threadIdx.x;  // 0..131071
  int mat = e >> 16;
  int rem = e & 65535;
  int quadrant = rem >> 14;
  int li = rem & 16383;
  const float* p = partials + ((size_t)(mat * 4 + quadrant) * 16) * 16384 + li;
  float g = 0.f;
#pragma unroll
  for (int kc = 0; kc < 16; ++kc) g += p[(size_t)kc * 16384];
  int rl = li >> 7, cl = li & 127;
  int gr = (quadrant >> 1) * 128 + rl;
  int gc = (quadrant & 1) * 128 + cl;
  if (gr == gc) g -= 1.f;
  float s = g * g;
#pragma unroll
  for (int off = 32; off > 0; off >>= 1) s += __shfl_down(s, off, 64);
  __shared__ float wsum[4];
  int wave = threadIdx.x >> 6, lane = threadIdx.x & 63;
  if (lane == 0) wsum[wave] = s;
  __syncthreads();
  if (threadIdx.x == 0) atomicAdd(d_out + 1, wsum[0] + wsum[1] + wsum[2] + wsum[3]);
}

// ---------------------------------------------------------------------------
extern "C" void kernel_launch(void* const* d_in, const int* in_sizes, int n_in,
                              void* d_out, int out_size, void* d_ws, size_t ws_size,
                              hipStream_t stream) {
  const int* idx1 = (const int*)d_in[0];
  const int* idx2 = (const int*)d_in[1];
  const float* trans = (const float*)d_in[2];
  const float* e1 = (const float*)d_in[3];
  const float* e2 = (const float*)d_in[4];
  float* out = (float*)d_out;

  char* ws = (char*)d_ws;
  unsigned short* En1 = (unsigned short*)(ws);                    // 4 MB
  unsigned short* En2 = (unsigned short*)(ws + (4u << 20));       // 4 MB
  unsigned short* ET1 = (unsigned short*)(ws + (8u << 20));       // 4 MB
  unsigned short* ET2 = (unsigned short*)(ws + (12u << 20));      // 4 MB
  float* partials = (float*)(ws + (16u << 20));                   // 8 MB

  hipLaunchKernelGGL(prep_kernel, dim3(128, 2), dim3(256), 0, stream,
                     e1, e2, idx1, idx2, En1, En2, ET1, ET2, out);
  hipLaunchKernelGGL(fused_kernel, dim3(4224), dim3(256), 0, stream,
                     En1, En2, ET1, ET2, trans, partials, out);
  hipLaunchKernelGGL(gram_reduce_kernel, dim3(512), dim3(256), 0, stream,
                     partials, out);
}

// Round 5
// 407.768 us; speedup vs baseline: 1.0534x; 1.0258x over previous
//
#include <hip/hip_runtime.h>
#include <hip/hip_bf16.h>

#define NUM 8192
#define DIM 256

typedef __bf16 bf16x8 __attribute__((ext_vector_type(8)));
typedef float f32x4 __attribute__((ext_vector_type(4)));

// float -> bf16 round-to-nearest-even
__device__ __forceinline__ unsigned short f2bf(float x) {
  unsigned int u = __float_as_uint(x);
  unsigned int r = (u + 0x7FFFu + ((u >> 16) & 1u)) >> 16;
  return (unsigned short)r;
}

// async global->LDS, 16B per lane. LDS dest must be wave-uniform base + lane*16.
__device__ __forceinline__ void async_copy16(const void* g, void* l) {
  __builtin_amdgcn_global_load_lds(
      (const __attribute__((address_space(1))) void*)g,
      (__attribute__((address_space(3))) void*)l,
      16, 0, 0);
}

// ---------------------------------------------------------------------------
// prep: gather rows, compute row 1/||x||, write normalized bf16 (row-major)
// and raw bf16 transposed ET [DIM][NUM]. Also zeroes d_out (replaces memset).
// grid (128, 2), block 256
// ---------------------------------------------------------------------------
__global__ __launch_bounds__(256) void prep_kernel(
    const float* __restrict__ e1, const float* __restrict__ e2,
    const int* __restrict__ idx1, const int* __restrict__ idx2,
    unsigned short* __restrict__ En1, unsigned short* __restrict__ En2,
    unsigned short* __restrict__ ET1, unsigned short* __restrict__ ET2,
    float* __restrict__ d_out) {
  __shared__ float tile[64][260];  // 260: keeps float4 16B alignment per row
  __shared__ float rinv[64];
  const int t = threadIdx.x;
  const int mat = blockIdx.y;
  if (blockIdx.x == 0 && mat == 0 && t < 2) d_out[t] = 0.f;
  const float* E = mat ? e2 : e1;
  const int* idx = mat ? idx2 : idx1;
  unsigned short* En = mat ? En2 : En1;
  unsigned short* ET = mat ? ET2 : ET1;
  const int r0 = blockIdx.x * 64;

  // load 64 gathered rows x 256 cols (fp32, coalesced float4)
#pragma unroll
  for (int p = 0; p < 16; ++p) {
    int flat = p * 256 + t;   // float4 id, 4096 total = 64 rows * 64
    int row = flat >> 6;
    int c4 = flat & 63;
    int src = idx[r0 + row];
    float4 v = *(const float4*)(E + (size_t)src * DIM + c4 * 4);
    *(float4*)(&tile[row][c4 * 4]) = v;
  }
  __syncthreads();

  // row energies: 4 threads per row; column-interleaved (stride 4) to spread
  // banks: bank = (4*row + 4*q + part) % 32 -> worst 2-way (free)
  {
    int row = t >> 2, part = t & 3;
    float s = 0.f;
#pragma unroll
    for (int q = 0; q < 64; ++q) {
      float x = tile[row][q * 4 + part];
      s += x * x;
    }
    s += __shfl_xor(s, 1, 64);
    s += __shfl_xor(s, 2, 64);
    if (part == 0) rinv[row] = rsqrtf(s);
  }
  __syncthreads();

  // write normalized bf16, row-major
#pragma unroll
  for (int p = 0; p < 16; ++p) {
    int flat = p * 256 + t;
    int row = flat >> 6;
    int c4 = flat & 63;
    float ri = rinv[row];
    float a = tile[row][c4 * 4 + 0] * ri;
    float b = tile[row][c4 * 4 + 1] * ri;
    float c = tile[row][c4 * 4 + 2] * ri;
    float d = tile[row][c4 * 4 + 3] * ri;
    uint2 o;
    o.x = (unsigned int)f2bf(a) | ((unsigned int)f2bf(b) << 16);
    o.y = (unsigned int)f2bf(c) | ((unsigned int)f2bf(d) << 16);
    *(uint2*)(En + (size_t)(r0 + row) * DIM + c4 * 4) = o;
  }

  // write raw bf16 transposed: ET[c][r0..r0+64]
  {
    int g = t >> 5;
    int j = t & 31;
#pragma unroll
    for (int cc = 0; cc < 32; ++cc) {
      int c = g * 32 + cc;
      unsigned int lo = f2bf(tile[2 * j][c]);
      unsigned int hi = f2bf(tile[2 * j + 1][c]);
      *(unsigned int*)(ET + (size_t)c * NUM + r0 + 2 * j) = lo | (hi << 16);
    }
  }
}

// ---------------------------------------------------------------------------
// Shared tile machinery: 128x128 output tile, BK=64, 4 waves (64x64 each),
// XOR-swizzled LDS (logical chunk c of row r stored at physical c^(r&7)).
// ---------------------------------------------------------------------------
#define TILE_STAGE(GA, GB, STRIDE, COLBASE)                                   \
  {                                                                           \
    _Pragma("unroll")                                                         \
    for (int p = 0; p < 4; ++p) {                                             \
      int flat = p * 256 + t;                                                 \
      int row = flat >> 3, seg = flat & 7;                                    \
      int segx = seg ^ (row & 7);                                             \
      async_copy16((GA) + (size_t)row * (STRIDE) + (COLBASE) + segx * 8,      \
                   As + row * 64 + seg * 8);                                  \
    }                                                                         \
    _Pragma("unroll")                                                         \
    for (int p = 0; p < 4; ++p) {                                             \
      int flat = p * 256 + t;                                                 \
      int row = flat >> 3, seg = flat & 7;                                    \
      int segx = seg ^ (row & 7);                                             \
      async_copy16((GB) + (size_t)row * (STRIDE) + (COLBASE) + segx * 8,      \
                   Bs + row * 64 + seg * 8);                                  \
    }                                                                         \
  }

#define TILE_COMPUTE()                                                        \
  _Pragma("unroll")                                                           \
  for (int ks = 0; ks < 2; ++ks) {                                            \
    bf16x8 aF[4], bF[4];                                                      \
    const int swz = (ks * 4 + quad) ^ (l15 & 7);                              \
    _Pragma("unroll")                                                         \
    for (int i = 0; i < 4; ++i)                                               \
      aF[i] = *(const bf16x8*)(As + (wr + i * 16 + l15) * 64 + swz * 8);      \
    _Pragma("unroll")                                                         \
    for (int j = 0; j < 4; ++j)                                               \
      bF[j] = *(const bf16x8*)(Bs + (wc + j * 16 + l15) * 64 + swz * 8);      \
    _Pragma("unroll")                                                         \
    for (int i = 0; i < 4; ++i)                                               \
      _Pragma("unroll")                                                       \
      for (int j = 0; j < 4; ++j)                                             \
        acc[i][j] = __builtin_amdgcn_mfma_f32_16x16x32_bf16(aF[i], bF[j],     \
                                                            acc[i][j], 0, 0, 0); \
  }

#define GW_DOT(C, W)                                                          \
  sum += (W).x * (1.f - __expf((C).x - 1.f));                                 \
  sum += (W).y * (1.f - __expf((C).y - 1.f));                                 \
  sum += (W).z * (1.f - __expf((C).z - 1.f));                                 \
  sum += (W).w * (1.f - __expf((C).w - 1.f));

// ---------------------------------------------------------------------------
// fused: blocks 0..127 = gram partials (G = ET(128 rows) @ ET(128 rows)^T over
// a 512-wide K chunk); blocks 128..4223 = main cos/trans tile kernel.
// R1 structure (best measured: 412.3 µs): plain __syncthreads K-loop, default
// block mapping (R4's XCD swizzle regressed ~6 µs — reverted), 16-deep MLP
// trans prefetch split around the last compute. Cross-block co-residency
// (3 blocks/CU @ 32 KB LDS) provides the GEMM/trans-stream overlap; intra-
// block pipelining attempts (R2 reg-prefetch, R3 trans-in-LDS) both lost to
// the register-pressure / occupancy cost they paid.
// ---------------------------------------------------------------------------
__global__ __launch_bounds__(256) void fused_kernel(
    const unsigned short* __restrict__ En1,
    const unsigned short* __restrict__ En2,
    const unsigned short* __restrict__ ET1,
    const unsigned short* __restrict__ ET2,
    const float* __restrict__ trans,
    float* __restrict__ partials,
    float* __restrict__ d_out) {
  __shared__ unsigned short As[128 * 64];
  __shared__ unsigned short Bs[128 * 64];
  const int bid = blockIdx.x;
  const int t = threadIdx.x;
  const int wave = t >> 6, lane = t & 63;
  const int quad = lane >> 4, l15 = lane & 15;
  const int wr = (wave >> 1) * 64, wc = (wave & 1) * 64;

  f32x4 acc[4][4];
#pragma unroll
  for (int i = 0; i < 4; ++i)
#pragma unroll
    for (int j = 0; j < 4; ++j) {
      acc[i][j].x = 0.f; acc[i][j].y = 0.f; acc[i][j].z = 0.f; acc[i][j].w = 0.f;
    }

  if (bid < 128) {
    // ---- gram path: bid = (mat*4 + quadrant)*16 + kc ----
    const int mat = bid >> 6;
    const int quadrant = (bid >> 4) & 3;
    const int kc = bid & 15;
    const unsigned short* ET = mat ? ET2 : ET1;
    const int qi = quadrant >> 1, qj = quadrant & 1;
    const unsigned short* gA = ET + (size_t)(qi * 128) * NUM + kc * 512;
    const unsigned short* gB = ET + (size_t)(qj * 128) * NUM + kc * 512;

    for (int kk = 0; kk < 8; ++kk) {
      TILE_STAGE(gA, gB, NUM, kk * 64);
      asm volatile("s_waitcnt vmcnt(0)" ::: "memory");
      __syncthreads();
      TILE_COMPUTE();
      if (kk < 7) __syncthreads();
    }

    float* pw = partials + (size_t)bid * 16384;
#pragma unroll
    for (int i = 0; i < 4; ++i)
#pragma unroll
      for (int r = 0; r < 4; ++r) {
        int rl = wr + i * 16 + quad * 4 + r;
#pragma unroll
        for (int j = 0; j < 4; ++j) {
          int cl = wc + j * 16 + l15;
          float v = (r == 0) ? acc[i][j].x : (r == 1) ? acc[i][j].y
                  : (r == 2) ? acc[i][j].z : acc[i][j].w;
          pw[rl * 128 + cl] = v;
        }
      }
  } else {
    // ---- main path: OPERAND-SWAPPED 128x128 tile, acc = cos^T ----
    const int g = bid - 128;  // default mapping (R1) — best measured
    const int bx = g & 63;   // En2 tile
    const int by = g >> 6;   // En1 tile
    const unsigned short* gA = En2 + (size_t)(bx * 128) * DIM;
    const unsigned short* gB = En1 + (size_t)(by * 128) * DIM;

    for (int kk = 0; kk < 3; ++kk) {  // K = 256, BK = 64
      TILE_STAGE(gA, gB, DIM, kk * 64);
      asm volatile("s_waitcnt vmcnt(0)" ::: "memory");
      __syncthreads();
      TILE_COMPUTE();
      __syncthreads();
    }
    // last K step: after the barrier, prefetch half the trans tile so the
    // HBM latency hides under the final 32 MFMAs. Half only (+32 VGPR peak)
    // to stay under the 170-VGPR / 3-waves-per-SIMD cliff.
    TILE_STAGE(gA, gB, DIM, 3 * 64);
    asm volatile("s_waitcnt vmcnt(0)" ::: "memory");
    __syncthreads();
    f32x4 tw0[4], tw1[4];
#pragma unroll
    for (int j = 0; j < 4; ++j) {
      size_t r1 = (size_t)(by * 128 + wc + j * 16 + l15);
      size_t cb = (size_t)(bx * 128 + wr + quad * 4);
      tw0[j] = __builtin_nontemporal_load((const f32x4*)(trans + r1 * NUM + cb));
      tw1[j] = __builtin_nontemporal_load((const f32x4*)(trans + r1 * NUM + cb + 16));
    }
    TILE_COMPUTE();

    // epilogue: acc[i][j] reg r holds cos(En1[by*128+wc+j*16+l15],
    //                                    En2[bx*128+wr+i*16+quad*4+r])
    f32x4 tw2[4], tw3[4];
#pragma unroll
    for (int j = 0; j < 4; ++j) {
      size_t r1 = (size_t)(by * 128 + wc + j * 16 + l15);
      size_t cb = (size_t)(bx * 128 + wr + quad * 4);
      tw2[j] = __builtin_nontemporal_load((const f32x4*)(trans + r1 * NUM + cb + 32));
      tw3[j] = __builtin_nontemporal_load((const f32x4*)(trans + r1 * NUM + cb + 48));
    }
    float sum = 0.f;
#pragma unroll
    for (int j = 0; j < 4; ++j) {
      GW_DOT(acc[0][j], tw0[j]);
      GW_DOT(acc[1][j], tw1[j]);
      GW_DOT(acc[2][j], tw2[j]);
      GW_DOT(acc[3][j], tw3[j]);
    }
#pragma unroll
    for (int off = 32; off > 0; off >>= 1) sum += __shfl_down(sum, off, 64);
    __shared__ float wsum[4];
    if (lane == 0) wsum[wave] = sum;
    __syncthreads();
    if (t == 0) atomicAdd(d_out, wsum[0] + wsum[1] + wsum[2] + wsum[3]);
  }
}

// ---------------------------------------------------------------------------
// gram reduce: sum k-chunk partials, subtract I, square, reduce -> d_out[1].
// f32x4 per thread (grid 128): 16 strided dwordx4 loads -> 4x the MLP of the
// scalar version on the 8 MB partials sweep, identical coalescing.
// ---------------------------------------------------------------------------
__global__ __launch_bounds__(256) void gram_reduce_kernel(
    const float* __restrict__ partials, float* __restrict__ d_out) {
  int e4 = (blockIdx.x * 256 + threadIdx.x) * 4;  // 0..131068, step 4
  int mat = e4 >> 16;
  int rem = e4 & 65535;
  int quadrant = rem >> 14;
  int li = rem & 16383;           // 4-aligned; all 4 elems in same slab/row
  const float* p = partials + ((size_t)(mat * 4 + quadrant) * 16) * 16384 + li;
  f32x4 g = {0.f, 0.f, 0.f, 0.f};
#pragma unroll
  for (int kc = 0; kc < 16; ++kc) {
    f32x4 v = *(const f32x4*)(p + (size_t)kc * 16384);
    g.x += v.x; g.y += v.y; g.z += v.z; g.w += v.w;
  }
  int rl = li >> 7, cl = li & 127;  // rl same for all 4; cl..cl+3
  int gr = (quadrant >> 1) * 128 + rl;
  int gc = (quadrant & 1) * 128 + cl;
  if (gr == gc + 0) g.x -= 1.f;
  if (gr == gc + 1) g.y -= 1.f;
  if (gr == gc + 2) g.z -= 1.f;
  if (gr == gc + 3) g.w -= 1.f;
  float s = g.x * g.x + g.y * g.y + g.z * g.z + g.w * g.w;
#pragma unroll
  for (int off = 32; off > 0; off >>= 1) s += __shfl_down(s, off, 64);
  __shared__ float wsum[4];
  int wave = threadIdx.x >> 6, lane = threadIdx.x & 63;
  if (lane == 0) wsum[wave] = s;
  __syncthreads();
  if (threadIdx.x == 0) atomicAdd(d_out + 1, wsum[0] + wsum[1] + wsum[2] + wsum[3]);
}

// ---------------------------------------------------------------------------
extern "C" void kernel_launch(void* const* d_in, const int* in_sizes, int n_in,
                              void* d_out, int out_size, void* d_ws, size_t ws_size,
                              hipStream_t stream) {
  const int* idx1 = (const int*)d_in[0];
  const int* idx2 = (const int*)d_in[1];
  const float* trans = (const float*)d_in[2];
  const float* e1 = (const float*)d_in[3];
  const float* e2 = (const float*)d_in[4];
  float* out = (float*)d_out;

  char* ws = (char*)d_ws;
  unsigned short* En1 = (unsigned short*)(ws);                    // 4 MB
  unsigned short* En2 = (unsigned short*)(ws + (4u << 20));       // 4 MB
  unsigned short* ET1 = (unsigned short*)(ws + (8u << 20));       // 4 MB
  unsigned short* ET2 = (unsigned short*)(ws + (12u << 20));      // 4 MB
  float* partials = (float*)(ws + (16u << 20));                   // 8 MB

  hipLaunchKernelGGL(prep_kernel, dim3(128, 2), dim3(256), 0, stream,
                     e1, e2, idx1, idx2, En1, En2, ET1, ET2, out);
  hipLaunchKernelGGL(fused_kernel, dim3(4224), dim3(256), 0, stream,
                     En1, En2, ET1, ET2, trans, partials, out);
  hipLaunchKernelGGL(gram_reduce_kernel, dim3(128), dim3(256), 0, stream,
                     partials, out);
}